// Round 1
// baseline (89.623 us; speedup 1.0000x reference)
//
#include <hip/hip_runtime.h>
#include <hip/hip_bf16.h>

// TrajectoryRasterizer: heat[b,t,h,w] = sum_o exp(-0.5*((lat[h]-lat_t)^2+(lon[w]-lon_t)^2)/sigma^2)
// then per-(b,t) max-normalize. Separable: exp(a+b)=exp(a)*exp(b) -> rank-32
// outer product per image. b*t=64, o=32, h=181, w=360.

#define NH 181
#define NW 360
#define NO 32
#define NIMG 64
#define NCHUNK 4
#define ROWS_PER_CHUNK 46  // ceil(181/4)

__global__ __launch_bounds__(384) void traj_raster_kernel(
    const float* __restrict__ traj,   // (64, 32, 2)
    const float* __restrict__ lat,    // (181,)
    const float* __restrict__ lon,    // (360,)
    float* __restrict__ out,          // (64, 181, 360)
    unsigned int* __restrict__ maxbuf // (64,) as uint-encoded nonneg floats, pre-zeroed
) {
    const int img = blockIdx.x;     // 0..63
    const int chunk = blockIdx.y;   // 0..3
    const int tid = threadIdx.x;

    __shared__ float fs[NO][NH];    // lat-direction gaussians
    __shared__ float gs[NO][NW];    // lon-direction gaussians
    __shared__ float wavemax[6];

    const float inv_sigma2 = 1.0f / (2.5f * 2.5f + 1e-8f);

    // Stage separable gaussian factors into LDS (cheap: 17312 exps/block).
    for (int i = tid; i < NO * NH; i += 384) {
        const int o = i / NH, h = i - o * NH;
        const float d = lat[h] - traj[(img * NO + o) * 2 + 0];
        fs[o][h] = __expf(-0.5f * inv_sigma2 * d * d);
    }
    for (int i = tid; i < NO * NW; i += 384) {
        const int o = i / NW, w = i - o * NW;
        const float d = lon[w] - traj[(img * NO + o) * 2 + 1];
        gs[o][w] = __expf(-0.5f * inv_sigma2 * d * d);
    }
    __syncthreads();

    float lmax = 0.0f;
    const int w = tid;
    if (w < NW) {
        // Cache this column's 32 lon-gaussians in registers.
        float greg[NO];
        #pragma unroll
        for (int o = 0; o < NO; ++o) greg[o] = gs[o][w];

        const int h0 = chunk * ROWS_PER_CHUNK;
        const int h1 = min(h0 + ROWS_PER_CHUNK, NH);
        float* __restrict__ outp = out + (size_t)img * NH * NW;

        for (int h = h0; h < h1; ++h) {
            float acc = 0.0f;
            #pragma unroll
            for (int o = 0; o < NO; ++o) {
                acc += greg[o] * fs[o][h];  // fs read is wave-broadcast (same addr)
            }
            outp[h * NW + w] = acc;
            lmax = fmaxf(lmax, acc);
        }
    }

    // Block max reduction: wave shuffle, then across 6 waves via LDS.
    #pragma unroll
    for (int off = 32; off > 0; off >>= 1) {
        lmax = fmaxf(lmax, __shfl_down(lmax, off, 64));
    }
    if ((tid & 63) == 0) wavemax[tid >> 6] = lmax;
    __syncthreads();
    if (tid == 0) {
        float m = wavemax[0];
        #pragma unroll
        for (int i = 1; i < 6; ++i) m = fmaxf(m, wavemax[i]);
        // Nonneg floats: uint bit-pattern ordering == value ordering.
        atomicMax(&maxbuf[img], __float_as_uint(m));
    }
}

__global__ __launch_bounds__(256) void traj_norm_kernel(
    float* __restrict__ out,
    const unsigned int* __restrict__ maxbuf
) {
    const int PIX4_PER_IMG = NH * NW / 4;       // 16290
    const int TOT4 = NIMG * PIX4_PER_IMG;       // 1,042,560
    int i4 = blockIdx.x * blockDim.x + threadIdx.x;
    if (i4 >= TOT4) return;
    const int img = i4 / PIX4_PER_IMG;
    const float m = __uint_as_float(maxbuf[img]);
    const float s = 1.0f / (m + 1e-8f);
    float4 v = ((float4*)out)[i4];
    v.x *= s; v.y *= s; v.z *= s; v.w *= s;
    ((float4*)out)[i4] = v;
}

extern "C" void kernel_launch(void* const* d_in, const int* in_sizes, int n_in,
                              void* d_out, int out_size, void* d_ws, size_t ws_size,
                              hipStream_t stream) {
    const float* traj = (const float*)d_in[0];  // (4,16,32,2) = 4096 floats
    const float* lat  = (const float*)d_in[1];  // (181,)
    const float* lon  = (const float*)d_in[2];  // (360,)
    float* out = (float*)d_out;                 // (4,16,181,360)
    unsigned int* maxbuf = (unsigned int*)d_ws;

    // Zero the per-image max slots (ws is poisoned to 0xAA before every launch).
    hipMemsetAsync(maxbuf, 0, NIMG * sizeof(unsigned int), stream);

    dim3 gridA(NIMG, NCHUNK);
    traj_raster_kernel<<<gridA, 384, 0, stream>>>(traj, lat, lon, out, maxbuf);

    const int TOT4 = NIMG * NH * NW / 4;
    traj_norm_kernel<<<(TOT4 + 255) / 256, 256, 0, stream>>>(out, maxbuf);
}